// Round 19
// baseline (515.677 us; speedup 1.0000x reference)
//
#include <hip/hip_runtime.h>
#include <cstdint>
#include <cstddef>

// ---------------------------------------------------------------------------
// Shapes: x (2,8,96,96,192) fp32 ; windows 1x8x8 ; NH=2 ; hd=96 ; L=512 ; MLP 768
// tokens N = 147456 ; Bp = 288 ; Dn = 8
// ---------------------------------------------------------------------------

typedef float   f32x4  __attribute__((ext_vector_type(4)));
typedef float   f32x2  __attribute__((ext_vector_type(2)));
typedef __bf16  bf16x8 __attribute__((ext_vector_type(8)));
typedef unsigned int   u32x4  __attribute__((ext_vector_type(4)));
typedef unsigned short u16x4  __attribute__((ext_vector_type(4)));

#define DEVI __device__ __forceinline__

DEVI float bf2f(unsigned short u) {
    union { unsigned int i; float f; } v; v.i = ((unsigned int)u) << 16; return v.f;
}
DEVI unsigned short f2bf(float f) {
    unsigned int u = __builtin_bit_cast(unsigned int, f);
    unsigned int r = u + 0x7fffu + ((u >> 16) & 1u);   // RNE
    return (unsigned short)(r >> 16);
}
// sigmoid-form GELU: v * sigmoid(1.702 v) (validated R15, absmax 0.03125)
DEVI float gelu_sig(float v) {
    float e = __expf(-1.702f * v);
    return v * __builtin_amdgcn_rcpf(1.f + e);
}
// pack 4 f32 -> 4 fp8 e4m3 (OCP) in one u32
DEVI unsigned int pk_fp8x4(float a, float b, float c, float d) {
    int v = __builtin_amdgcn_cvt_pk_fp8_f32(a, b, 0, false);
    v = __builtin_amdgcn_cvt_pk_fp8_f32(c, d, v, true);
    return (unsigned int)v;
}
DEVI f32x4 mfma_fp8(unsigned long long a, unsigned long long b, f32x4 c) {
    return __builtin_amdgcn_mfma_f32_16x16x32_fp8_fp8((long)a, (long)b, c, 0, 0, 0);
}

// async global->LDS, 16B per lane; LDS dest is wave-uniform base + lane*16
typedef __attribute__((address_space(3))) unsigned char       lds_u8;
typedef __attribute__((address_space(1))) const unsigned char g_u8;
DEVI void gl_lds16(const void* g, void* l) {
    __builtin_amdgcn_global_load_lds((g_u8*)g, (lds_u8*)l, 16, 0, 0);
}

// ---------------------------------------------------------------------------
// K0: convert + pad weights: wq/wo/w1 -> bf16 (LN gammas folded), w2 -> fp8.
// ---------------------------------------------------------------------------
__global__ __launch_bounds__(256) void k_wconv(const float* __restrict__ wqkv,
                                               const float* __restrict__ wout,
                                               const float* __restrict__ wfc1,
                                               const float* __restrict__ wfc2,
                                               const float* __restrict__ n3g,
                                               const float* __restrict__ n4g,
                                               unsigned short* __restrict__ oq,
                                               unsigned short* __restrict__ oo,
                                               unsigned short* __restrict__ o1,
                                               unsigned short* __restrict__ o2f8) {
    int i = blockIdx.x * 256 + threadIdx.x;
    if (i < 122880) {                       // [640][192] bf16
        int r = i / 192, c = i - r * 192;
        oq[i] = (r < 576) ? f2bf(wqkv[i] * n3g[c]) : (unsigned short)0;
    } else if (i < 172032) {                // [256][192] bf16
        int j = i - 122880; int r = j / 192;
        oo[j] = (r < 192) ? f2bf(wout[j]) : (unsigned short)0;
    } else if (i < 319488) {                // [768][192] bf16
        int j = i - 172032; int c = j % 192;
        o1[j] = f2bf(wfc1[j] * n4g[c]);
    } else if (i < 417792) {                // [256][768] fp8, 2 elems/thread
        int j = i - 319488;                  // pair index over [256][384]
        int r = j / 384;
        float a = 0.f, b = 0.f;
        if (r < 192) { a = wfc2[2 * j]; b = wfc2[2 * j + 1]; }
        int pk = __builtin_amdgcn_cvt_pk_fp8_f32(a, b, 0, false);
        o2f8[j] = (unsigned short)pk;        // fp8 pairs
    }
}

// ---------------------------------------------------------------------------
// K0b: effective biases folding LN beta, plus w1 row-sums (for LN4 fold).
// ---------------------------------------------------------------------------
__global__ __launch_bounds__(256) void k_bias(const float* __restrict__ wqkv,
                                              const float* __restrict__ bqkv,
                                              const float* __restrict__ n3b,
                                              const float* __restrict__ wfc1,
                                              const float* __restrict__ bfc1,
                                              const float* __restrict__ n4b,
                                              const float* __restrict__ n4g,
                                              float* __restrict__ beffq,
                                              float* __restrict__ beff1,
                                              float* __restrict__ w1sum) {
    int wid = blockIdx.x * 4 + (threadIdx.x >> 6);
    int lane = threadIdx.x & 63;
    if (wid < 576) {
        const float* wrow = wqkv + (size_t)wid * 192;
        float s = wrow[lane] * n3b[lane] + wrow[lane + 64] * n3b[lane + 64]
                + wrow[lane + 128] * n3b[lane + 128];
#pragma unroll
        for (int off = 32; off; off >>= 1) s += __shfl_xor(s, off);
        if (lane == 0) beffq[wid] = bqkv[wid] + s;
    } else {
        int h = wid - 576;
        const float* wrow = wfc1 + (size_t)h * 192;
        float s = wrow[lane] * n4b[lane] + wrow[lane + 64] * n4b[lane + 64]
                + wrow[lane + 128] * n4b[lane + 128];
        float s2 = wrow[lane] * n4g[lane] + wrow[lane + 64] * n4g[lane + 64]
                 + wrow[lane + 128] * n4g[lane + 128];
#pragma unroll
        for (int off = 32; off; off >>= 1) { s += __shfl_xor(s, off); s2 += __shfl_xor(s2, off); }
        if (lane == 0) { beff1[h] = bfc1[h] + s; w1sum[h] = s2; }
    }
}

// ---------------------------------------------------------------------------
// K1: LayerNorm(norm3) WITHOUT affine + window partition -> h bf16.
// ---------------------------------------------------------------------------
__global__ __launch_bounds__(256) void k_ln3(const float* __restrict__ x,
                                             unsigned short* __restrict__ h) {
    int w = threadIdx.x >> 6, lane = threadIdx.x & 63;
    int token = blockIdx.x * 4 + w;
    const float* xp = x + (size_t)token * 192;
    float v0 = xp[lane], v1 = xp[lane + 64], v2 = xp[lane + 128];
    float s = v0 + v1 + v2;
#pragma unroll
    for (int off = 32; off; off >>= 1) s += __shfl_xor(s, off);
    float mean = s * (1.f / 192.f);
    float d0 = v0 - mean, d1 = v1 - mean, d2 = v2 - mean;
    float q = d0 * d0 + d1 * d1 + d2 * d2;
#pragma unroll
    for (int off = 32; off; off >>= 1) q += __shfl_xor(q, off);
    float rs = rsqrtf(q * (1.f / 192.f) + 1e-5f);
    int b  = token / (8 * 96 * 96);
    int r0 = token - b * (8 * 96 * 96);
    int d  = r0 / (96 * 96);
    int r1 = r0 - d * (96 * 96);
    int hh = r1 / 96;
    int ww = r1 - hh * 96;
    int bp = b * 144 + (hh >> 3) * 12 + (ww >> 3);
    int l  = d * 64 + (hh & 7) * 8 + (ww & 7);
    unsigned short* hp = h + ((size_t)bp * 512 + l) * 192;
    hp[lane]       = f2bf(d0 * rs);
    hp[lane + 64]  = f2bf(d1 * rs);
    hp[lane + 128] = f2bf(d2 * rs);
}

// ---------------------------------------------------------------------------
// K5: LN4 statistics only: per ybf row write (mu, rs). 1.2 MB output.
// ---------------------------------------------------------------------------
__global__ __launch_bounds__(256) void k_stats(const unsigned short* __restrict__ yb,
                                               float* __restrict__ st) {
    int sub = threadIdx.x >> 5, tl = threadIdx.x & 31;
    size_t row = (size_t)blockIdx.x * 8 + sub;
    const unsigned int* rp = reinterpret_cast<const unsigned int*>(yb + row * 192);
    float v[6];
#pragma unroll
    for (int j = 0; j < 3; j++) {
        unsigned int w = rp[tl + 32 * j];
        v[2 * j]     = bf2f((unsigned short)(w & 0xffffu));
        v[2 * j + 1] = bf2f((unsigned short)(w >> 16));
    }
    float s = v[0] + v[1] + v[2] + v[3] + v[4] + v[5];
#pragma unroll
    for (int off = 1; off < 32; off <<= 1) s += __shfl_xor(s, off);
    float mean = s * (1.f / 192.f);
    float q = 0.f;
#pragma unroll
    for (int j = 0; j < 6; j++) { float d = v[j] - mean; q += d * d; }
#pragma unroll
    for (int off = 1; off < 32; off <<= 1) q += __shfl_xor(q, off);
    float rs = rsqrtf(q * (1.f / 192.f) + 1e-5f);
    if (tl == 0) { st[row * 2] = mean; st[row * 2 + 1] = rs; }
}

// ---------------------------------------------------------------------------
// K2: 128xBN GEMM (BN = NF*32), BK-parameterized, counted-vmcnt pipeline.
// BK=32: 3-buffer 2-DEEP prefetch (fc2's proven schedule): tiles t+1,t+2 in
// flight across compute; vmcnt ladder 8/4/0; LDS 48 KB. Swizzle (r>>1)&3.
// BK=64 (oproj): 2-buffer 1-deep as before.
// ---------------------------------------------------------------------------
template <int EPI, int K, int NF, int BK>
__global__ __launch_bounds__(256) void k_gemm128(const unsigned short* __restrict__ A,
                                                 const unsigned short* __restrict__ Bw,
                                                 const float* __restrict__ bias,
                                                 unsigned short* __restrict__ outb,
                                                 unsigned short* __restrict__ vt,
                                                 const float* __restrict__ res,
                                                 unsigned char* __restrict__ outf8,
                                                 const float* __restrict__ stats,
                                                 const float* __restrict__ wsum) {
    constexpr int NBUF = (BK == 32) ? 3 : 2;
    __shared__ unsigned short As[NBUF][128 * BK];
    __shared__ unsigned short Bs[NBUF][NF * 32 * BK];
    const int tid = threadIdx.x;
    const int nwg = gridDim.x * gridDim.y;
    const int flat = blockIdx.y * gridDim.x + blockIdx.x;
    const int swz = (flat & 7) * (nwg >> 3) + (flat >> 3);
    const int bx = swz % gridDim.x, by = swz / gridDim.x;
    const int row0 = by * 128, col0 = bx * (NF * 32);
    const int wv = tid >> 6, lane = tid & 63, lr = lane & 15, lg = lane >> 4;
    const int wr = wv >> 1, wc = wv & 1;
    f32x4 acc[4][NF] = {};

    auto stage = [&](int t, int buf) {
        int k0 = t * BK;
        if constexpr (BK == 64) {
            const int sr = lane >> 3, sc = lane & 7;
#pragma unroll
            for (int i = 0; i < 4; i++) {
                int gq = wv * 4 + i;
                int r = gq * 8 + sr;
                int j = sc ^ (r & 7);
                gl_lds16(A + (size_t)(row0 + r) * K + k0 + j * 8, &As[buf][gq * 512]);
            }
#pragma unroll
            for (int i = 0; i < NF; i++) {
                int gq = wv * NF + i;
                int r = gq * 8 + sr;
                int j = sc ^ (r & 7);
                gl_lds16(Bw + (size_t)(col0 + r) * K + k0 + j * 8, &Bs[buf][gq * 512]);
            }
        } else {   // BK == 32: 1KB group = 16 rows x 4 chunks; swz const (r>>1)&3
            const int sr = lane >> 2, sc = lane & 3;
#pragma unroll
            for (int i = 0; i < 2; i++) {
                int g = wv * 2 + i;              // 8 groups of 16 rows
                int r = g * 16 + sr;
                int j = sc ^ ((r >> 1) & 3);
                gl_lds16(A + (size_t)(row0 + r) * K + k0 + j * 8, &As[buf][g * 512]);
            }
#pragma unroll
            for (int i = 0; i < 2; i++) {        // NF==4 -> 128 B rows
                int g = wv * 2 + i;
                int r = g * 16 + sr;
                int j = sc ^ ((r >> 1) & 3);
                gl_lds16(Bw + (size_t)(col0 + r) * K + k0 + j * 8, &Bs[buf][g * 512]);
            }
        }
    };

    const int NT = K / BK;
    stage(0, 0);
    if constexpr (BK == 32) stage(1, 1);
    int cur = 0;
    for (int t = 0; t < NT; ++t) {
        if constexpr (BK == 32) {
            if (t + 2 < NT) {
                stage(t + 2, (t + 2) % 3);       // 8 outstanding
                asm volatile("s_waitcnt vmcnt(8)" ::: "memory");   // tile t landed
            } else if (t + 1 < NT) {
                asm volatile("s_waitcnt vmcnt(4)" ::: "memory");
            } else {
                asm volatile("s_waitcnt vmcnt(0)" ::: "memory");
            }
        } else {
            if (t + 1 < NT) {
                stage(t + 1, (t + 1) & 1);
                if constexpr (NF == 4) asm volatile("s_waitcnt vmcnt(8)" ::: "memory");
                else                   asm volatile("s_waitcnt vmcnt(7)" ::: "memory");
            } else {
                asm volatile("s_waitcnt vmcnt(0)" ::: "memory");
            }
        }
        __builtin_amdgcn_sched_barrier(0);
        __builtin_amdgcn_s_barrier();
        __builtin_amdgcn_sched_barrier(0);
        if constexpr (BK == 64) {
#pragma unroll
            for (int kk = 0; kk < 64; kk += 32) {
                bf16x8 af[4], bf[NF];
#pragma unroll
                for (int m = 0; m < 4; m++) {
                    int r = wr * 64 + m * 16 + lr;
                    int j = ((kk >> 3) + lg) ^ (r & 7);
                    af[m] = __builtin_bit_cast(bf16x8,
                        *reinterpret_cast<const u32x4*>(&As[cur][r * 64 + j * 8]));
                }
#pragma unroll
                for (int n = 0; n < NF; n++) {
                    int r = wc * (NF * 16) + n * 16 + lr;
                    int j = ((kk >> 3) + lg) ^ (r & 7);
                    bf[n] = __builtin_bit_cast(bf16x8,
                        *reinterpret_cast<const u32x4*>(&Bs[cur][r * 64 + j * 8]));
                }
#pragma unroll
                for (int m = 0; m < 4; m++)
#pragma unroll
                    for (int n = 0; n < NF; n++)
                        acc[m][n] = __builtin_amdgcn_mfma_f32_16x16x32_bf16(bf[n], af[m], acc[m][n], 0, 0, 0);
            }
        } else {
            bf16x8 af[4], bf[NF];
#pragma unroll
            for (int m = 0; m < 4; m++) {
                int r = wr * 64 + m * 16 + lr;
                int j = lg ^ ((r >> 1) & 3);
                af[m] = __builtin_bit_cast(bf16x8,
                    *reinterpret_cast<const u32x4*>(&As[cur][r * 32 + j * 8]));
            }
#pragma unroll
            for (int n = 0; n < NF; n++) {
                int r = wc * (NF * 16) + n * 16 + lr;
                int j = lg ^ ((r >> 1) & 3);
                bf[n] = __builtin_bit_cast(bf16x8,
                    *reinterpret_cast<const u32x4*>(&Bs[cur][r * 32 + j * 8]));
            }
#pragma unroll
            for (int m = 0; m < 4; m++)
#pragma unroll
                for (int n = 0; n < NF; n++)
                    acc[m][n] = __builtin_amdgcn_mfma_f32_16x16x32_bf16(bf[n], af[m], acc[m][n], 0, 0, 0);
        }
        __builtin_amdgcn_sched_barrier(0);
        __builtin_amdgcn_s_barrier();
        __builtin_amdgcn_sched_barrier(0);
        cur = (cur + 1) % NBUF;
    }

#pragma unroll
    for (int m = 0; m < 4; m++) {
        const int arow = row0 + wr * 64 + m * 16 + lr;
        if constexpr (EPI == 0) {
#pragma unroll
            for (int n = 0; n < NF; n++) {
                const int colb = col0 + wc * (NF * 16) + n * 16 + lg * 4;
                if (colb < 384) {
                    f32x4 b4 = *reinterpret_cast<const f32x4*>(bias + colb);
                    float sc2 = (colb < 192) ? 0.1020620726159658f : 1.f;  // 1/sqrt(96) on q
                    u16x4 pk;
#pragma unroll
                    for (int rr = 0; rr < 4; rr++) pk[rr] = f2bf((acc[m][n][rr] + b4[rr]) * sc2);
                    *reinterpret_cast<u16x4*>(outb + (size_t)arow * 384 + colb) = pk;
                } else if (colb < 576) {
                    int head = (colb >= 480) ? 1 : 0;
                    int bp = arow >> 9, tok = arow & 511;
                    size_t vb = ((size_t)(bp * 2 + head) * 96 + (colb - 384 - head * 96)) * 512 + tok;
#pragma unroll
                    for (int rr = 0; rr < 4; rr++)
                        vt[vb + (size_t)rr * 512] = f2bf(acc[m][n][rr] + bias[colb + rr]);
                }
            }
        } else if constexpr (EPI == 1) {
            int bp = arow >> 9, l = arow & 511;
            int bb = bp / 144, p = bp - bb * 144;
            int hn = p / 12, wn = p - hn * 12;
            int dn = l >> 6, t_ = l & 63;
            size_t tok = ((size_t)((bb * 8 + dn) * 96 + hn * 8 + (t_ >> 3)) * 96 + wn * 8 + (t_ & 7));
#pragma unroll
            for (int n = 0; n < NF; n++) {
                const int colb = col0 + wc * (NF * 16) + n * 16 + lg * 4;   // < 192
                size_t idx = tok * 192 + colb;
                f32x4 r4 = *reinterpret_cast<const f32x4*>(res + idx);
                f32x4 b4 = *reinterpret_cast<const f32x4*>(bias + colb);
                u16x4 pk;
#pragma unroll
                for (int rr = 0; rr < 4; rr++) pk[rr] = f2bf(r4[rr] + acc[m][n][rr] + b4[rr]);
                *reinterpret_cast<u16x4*>(outb + idx) = pk;
            }
        } else {
            f32x2 st = *reinterpret_cast<const f32x2*>(stats + 2 * arow);   // mu, rs
#pragma unroll
            for (int n = 0; n < NF; n++) {
                const int colb = col0 + wc * (NF * 16) + n * 16 + lg * 4;   // < 768
                f32x4 b4 = *reinterpret_cast<const f32x4*>(bias + colb);
                f32x4 S4 = *reinterpret_cast<const f32x4*>(wsum + colb);
                float g0 = gelu_sig((acc[m][n][0] - st[0] * S4[0]) * st[1] + b4[0]);
                float g1 = gelu_sig((acc[m][n][1] - st[0] * S4[1]) * st[1] + b4[1]);
                float g2 = gelu_sig((acc[m][n][2] - st[0] * S4[2]) * st[1] + b4[2]);
                float g3 = gelu_sig((acc[m][n][3] - st[0] * S4[3]) * st[1] + b4[3]);
                *reinterpret_cast<unsigned int*>(outf8 + (size_t)arow * 768 + colb) =
                    pk_fp8x4(g0, g1, g2, g3);
            }
        }
    }
}

// ---------------------------------------------------------------------------
// K3: block-causal attention (unchanged).
// ---------------------------------------------------------------------------
__global__ __launch_bounds__(512) void k_attn(const unsigned short* __restrict__ qk,
                                              const unsigned short* __restrict__ vt,
                                              unsigned short* __restrict__ aout) {
    __shared__ unsigned short Ks[64][104];
    __shared__ unsigned short Vs[96][72];
    __shared__ unsigned short Ps[8][16][72];

    int bid = (blockIdx.x & 7) * 288 + (blockIdx.x >> 3);
    int bp = bid >> 3, rest = bid & 7, head = rest >> 2, pr = rest & 3;
    int tid = threadIdx.x, wv = tid >> 6, lane = tid & 63;
    int lr = lane & 15, lg = lane >> 4;
    int wq = wv & 3, wt = wv >> 2;
    int nk = 2 * pr + 2;

    size_t qrow0 = (size_t)bp * 512 + (size_t)(2 * pr + wt) * 64;
    const unsigned short* vbase = vt + (size_t)(bp * 2 + head) * 96 * 512;
    size_t krowb = (size_t)bp * 512;

    bf16x8 qf[3];
    {
        const unsigned short* qp = qk + (qrow0 + wq * 16 + lr) * 384 + head * 96 + lg * 8;
#pragma unroll
        for (int ks = 0; ks < 3; ks++)
            qf[ks] = __builtin_bit_cast(bf16x8, *reinterpret_cast<const u32x4*>(qp + ks * 32));
    }

    f32x4 o[6] = {};
    float m_ = -1e30f, lsum = 0.f;

    u32x4 sreg[3];
    auto issue = [&](int dnk) {
#pragma unroll
        for (int i = 0; i < 3; i++) {
            int c = tid + i * 512;
            if (c < 768) {
                int r = c / 12, cc = c - r * 12;
                sreg[i] = *reinterpret_cast<const u32x4*>(
                    qk + (krowb + dnk * 64 + r) * 384 + 192 + head * 96 + cc * 8);
            } else {
                int c2 = c - 768; int d = c2 >> 3, tb = c2 & 7;
                sreg[i] = *reinterpret_cast<const u32x4*>(
                    vbase + (size_t)d * 512 + dnk * 64 + tb * 8);
            }
        }
    };
    auto commit = [&]() {
#pragma unroll
        for (int i = 0; i < 3; i++) {
            int c = tid + i * 512;
            if (c < 768) {
                int r = c / 12, cc = c - r * 12;
                *reinterpret_cast<u32x4*>(&Ks[r][cc * 8]) = sreg[i];
            } else {
                int c2 = c - 768; int d = c2 >> 3, tb = c2 & 7;
                *reinterpret_cast<u32x4*>(&Vs[d][tb * 8]) = sreg[i];
            }
        }
    };

    issue(0);
    for (int dnk = 0; dnk < nk; ++dnk) {
        commit();
        __syncthreads();
        if (dnk + 1 < nk) issue(dnk + 1);
        if (wt == 1 || dnk < nk - 1) {
            f32x4 st[4] = {};
#pragma unroll
            for (int ks = 0; ks < 3; ks++) {
#pragma unroll
                for (int ct = 0; ct < 4; ct++) {
                    bf16x8 kf = __builtin_bit_cast(bf16x8,
                        *reinterpret_cast<const u32x4*>(&Ks[ct * 16 + lr][ks * 32 + lg * 8]));
                    st[ct] = __builtin_amdgcn_mfma_f32_16x16x32_bf16(kf, qf[ks], st[ct], 0, 0, 0);
                }
            }
            float mx = st[0][0];
#pragma unroll
            for (int ct = 0; ct < 4; ct++)
#pragma unroll
                for (int rr = 0; rr < 4; rr++) mx = fmaxf(mx, st[ct][rr]);
            mx = fmaxf(mx, __shfl_xor(mx, 16));
            mx = fmaxf(mx, __shfl_xor(mx, 32));
            float mnew = fmaxf(m_, mx);
            float corr = __expf(m_ - mnew);
            m_ = mnew;
            float ps = 0.f;
#pragma unroll
            for (int ct = 0; ct < 4; ct++) {
                u16x4 pk;
#pragma unroll
                for (int rr = 0; rr < 4; rr++) {
                    float pv = __expf(st[ct][rr] - mnew);
                    ps += pv;
                    pk[rr] = f2bf(pv);
                }
                *reinterpret_cast<u16x4*>(&Ps[wv][lr][ct * 16 + lg * 4]) = pk;
            }
            ps += __shfl_xor(ps, 16);
            ps += __shfl_xor(ps, 32);
            lsum = lsum * corr + ps;
#pragma unroll
            for (int rr = 0; rr < 4; rr++) {
                float cr = __shfl(corr, (lane & 48) | (lg * 4 + rr));
#pragma unroll
                for (int nf = 0; nf < 6; nf++) o[nf][rr] *= cr;
            }
#pragma unroll
            for (int kk = 0; kk < 2; kk++) {
                bf16x8 pf = __builtin_bit_cast(bf16x8,
                    *reinterpret_cast<const u32x4*>(&Ps[wv][lr][kk * 32 + lg * 8]));
#pragma unroll
                for (int nf = 0; nf < 6; nf++) {
                    bf16x8 vf = __builtin_bit_cast(bf16x8,
                        *reinterpret_cast<const u32x4*>(&Vs[nf * 16 + lr][kk * 32 + lg * 8]));
                    o[nf] = __builtin_amdgcn_mfma_f32_16x16x32_bf16(pf, vf, o[nf], 0, 0, 0);
                }
            }
        }
        __syncthreads();
    }

#pragma unroll
    for (int rr = 0; rr < 4; rr++) {
        float li = __shfl(lsum, (lane & 48) | (lg * 4 + rr));
        float inv = 1.f / li;
        size_t row = qrow0 + wq * 16 + lg * 4 + rr;
#pragma unroll
        for (int nf = 0; nf < 6; nf++)
            aout[row * 192 + head * 96 + nf * 16 + lr] = f2bf(o[nf][rr] * inv);
    }
}

// ---------------------------------------------------------------------------
// K6: fc2 fp8 x fp8 GEMM, 3-buffer 2-deep prefetch (unchanged).
// ---------------------------------------------------------------------------
__global__ __launch_bounds__(256) void k_fc2(const unsigned char* __restrict__ hid,
                                             const unsigned char* __restrict__ w2,
                                             const float* __restrict__ b2,
                                             const unsigned short* __restrict__ ybf,
                                             float* __restrict__ out) {
    __shared__ unsigned char As[3][128 * 64];    // 24 KB
    __shared__ unsigned char Bs[3][128 * 64];    // 24 KB
    const int tid = threadIdx.x;
    const int nwg = gridDim.x * gridDim.y;
    const int flat = blockIdx.y * gridDim.x + blockIdx.x;
    const int swz = (flat & 7) * (nwg >> 3) + (flat >> 3);
    const int bx = swz % gridDim.x, by = swz / gridDim.x;
    const int row0 = by * 128, col0 = bx * 96;
    const int wv = tid >> 6, lane = tid & 63, lr = lane & 15, lg = lane >> 4;
    const int wr = wv >> 1, wc = wv & 1;
    const int sr4 = lane >> 2, sc4 = lane & 3;
    f32x4 acc[4][3] = {};

    auto stage = [&](int t, int buf) {
        int k0 = t * 64;
#pragma unroll
        for (int i = 0; i < 2; i++) {
            int g = wv * 2 + i;
            int r = g * 16 + sr4;
            int j = sc4 ^ (r & 3);
            gl_lds16(hid + (size_t)(row0 + r) * 768 + k0 + j * 16, &As[buf][g * 1024]);
        }
#pragma unroll
        for (int i = 0; i < 2; i++) {
            int g = wv * 2 + i;
            int r = g * 16 + sr4;
            int j = sc4 ^ (r & 3);
            gl_lds16(w2 + (size_t)(col0 + r) * 768 + k0 + j * 16, &Bs[buf][g * 1024]);
        }
    };

    stage(0, 0);
    stage(1, 1);
    int cur = 0;
    for (int t = 0; t < 12; ++t) {
        if (t + 2 < 12) {
            stage(t + 2, (t + 2) % 3);
            asm volatile("s_waitcnt vmcnt(8)" ::: "memory");
        } else if (t + 1 < 12) {
            asm volatile("s_waitcnt vmcnt(4)" ::: "memory");
        } else {
            asm volatile("s_waitcnt vmcnt(0)" ::: "memory");
        }
        __builtin_amdgcn_sched_barrier(0);
        __builtin_amdgcn_s_barrier();
        __builtin_amdgcn_sched_barrier(0);
#pragma unroll
        for (int kk = 0; kk < 2; kk++) {
            const int cc = kk * 2 + (lg >> 1);
            const int off = (lg & 1) * 8;
            unsigned long long af[4], bfr[3];
#pragma unroll
            for (int m = 0; m < 4; m++) {
                int r = wr * 64 + m * 16 + lr;
                int j = cc ^ (r & 3);
                af[m] = *reinterpret_cast<const unsigned long long*>(
                    &As[cur][r * 64 + j * 16 + off]);
            }
#pragma unroll
            for (int n = 0; n < 3; n++) {
                int r = wc * 48 + n * 16 + lr;
                int j = cc ^ (r & 3);
                bfr[n] = *reinterpret_cast<const unsigned long long*>(
                    &Bs[cur][r * 64 + j * 16 + off]);
            }
#pragma unroll
            for (int m = 0; m < 4; m++)
#pragma unroll
                for (int n = 0; n < 3; n++)
                    acc[m][n] = mfma_fp8(bfr[n], af[m], acc[m][n]);
        }
        __builtin_amdgcn_sched_barrier(0);
        __builtin_amdgcn_s_barrier();
        __builtin_amdgcn_sched_barrier(0);
        cur = (cur + 1) % 3;
    }

#pragma unroll
    for (int m = 0; m < 4; m++) {
        const int arow = row0 + wr * 64 + m * 16 + lr;
#pragma unroll
        for (int n = 0; n < 3; n++) {
            const int colb = col0 + wc * 48 + n * 16 + lg * 4;   // < 192
            size_t idx = (size_t)arow * 192 + colb;
            f32x4 b4 = *reinterpret_cast<const f32x4*>(b2 + colb);
            u16x4 rb = *reinterpret_cast<const u16x4*>(ybf + idx);
            f32x4 o4;
#pragma unroll
            for (int rr = 0; rr < 4; rr++) o4[rr] = bf2f(rb[rr]) + acc[m][n][rr] + b4[rr];
            *reinterpret_cast<f32x4*>(out + idx) = o4;
        }
    }
}

// ---------------------------------------------------------------------------
// Launcher. ws arena (~342 MB), unchanged from R18.
// d_out written only by k_fc2 (fully rewritten each call => replay safe).
// ---------------------------------------------------------------------------
extern "C" void kernel_launch(void* const* d_in, const int* in_sizes, int n_in,
                              void* d_out, int out_size, void* d_ws, size_t ws_size,
                              hipStream_t stream) {
    const float* x    = (const float*)d_in[0];
    const float* n3g  = (const float*)d_in[1];
    const float* n3b  = (const float*)d_in[2];
    const float* wqkv = (const float*)d_in[3];
    const float* bqkv = (const float*)d_in[4];
    const float* wout = (const float*)d_in[5];
    const float* bout = (const float*)d_in[6];
    const float* n4g  = (const float*)d_in[7];
    const float* n4b  = (const float*)d_in[8];
    const float* wfc1 = (const float*)d_in[9];
    const float* bfc1 = (const float*)d_in[10];
    const float* wfc2 = (const float*)d_in[11];
    const float* bfc2 = (const float*)d_in[12];
    float* out = (float*)d_out;

    char* ws = (char*)d_ws;
    unsigned short* qk     = (unsigned short*)(ws + 0);
    unsigned char*  hidden = (unsigned char*)(ws + 0);            // aliases qk (dead)
    unsigned short* vt     = (unsigned short*)(ws + 113246208);
    unsigned short* attn   = (unsigned short*)(ws + 169869312);
    unsigned short* ybf    = (unsigned short*)(ws + 226492416);
    unsigned short* h      = (unsigned short*)(ws + 283115520);
    unsigned short* wq_bf  = (unsigned short*)(ws + 339738624);
    unsigned short* wo_bf  = (unsigned short*)(ws + 339984384);
    unsigned short* w1_bf  = (unsigned short*)(ws + 340082688);
    unsigned short* w2_f8p = (unsigned short*)(ws + 340377600);   // fp8 pairs
    unsigned char*  w2_f8  = (unsigned char*)(ws + 340377600);
    float*          beffq  = (float*)(ws + 340574208);
    float*          beff1  = (float*)(ws + 340576512);
    float*          w1sum  = (float*)(ws + 340579584);
    float*          stats  = (float*)(ws + 340582656);            // [N][2] mu,rs

    k_wconv<<<1632, 256, 0, stream>>>(wqkv, wout, wfc1, wfc2, n3g, n4g, wq_bf, wo_bf, w1_bf, w2_f8p);
    k_bias<<<336, 256, 0, stream>>>(wqkv, bqkv, n3b, wfc1, bfc1, n4b, n4g, beffq, beff1, w1sum);
    k_ln3<<<36864, 256, 0, stream>>>(x, h);
    k_gemm128<0, 192, 4, 32><<<dim3(5, 1152), 256, 0, stream>>>(h, wq_bf, beffq, qk, vt, nullptr, nullptr, nullptr, nullptr);
    k_attn<<<2304, 512, 0, stream>>>(qk, vt, attn);
    k_gemm128<1, 192, 3, 64><<<dim3(2, 1152), 256, 0, stream>>>(attn, wo_bf, bout, ybf, nullptr, x, nullptr, nullptr, nullptr);
    k_stats<<<18432, 256, 0, stream>>>(ybf, stats);
    k_gemm128<2, 192, 4, 32><<<dim3(6, 1152), 256, 0, stream>>>(ybf, w1_bf, beff1, nullptr, nullptr, nullptr, hidden, stats, w1sum);
    k_fc2<<<dim3(2, 1152), 256, 0, stream>>>(hidden, w2_f8, bfc2, ybf, out);
}

// Round 20
// 507.122 us; speedup vs baseline: 1.0169x; 1.0169x over previous
//
#include <hip/hip_runtime.h>
#include <cstdint>
#include <cstddef>

// ---------------------------------------------------------------------------
// Shapes: x (2,8,96,96,192) fp32 ; windows 1x8x8 ; NH=2 ; hd=96 ; L=512 ; MLP 768
// tokens N = 147456 ; Bp = 288 ; Dn = 8
// ---------------------------------------------------------------------------

typedef float   f32x4  __attribute__((ext_vector_type(4)));
typedef float   f32x2  __attribute__((ext_vector_type(2)));
typedef __bf16  bf16x8 __attribute__((ext_vector_type(8)));
typedef unsigned int   u32x4  __attribute__((ext_vector_type(4)));
typedef unsigned short u16x4  __attribute__((ext_vector_type(4)));

#define DEVI __device__ __forceinline__

DEVI float bf2f(unsigned short u) {
    union { unsigned int i; float f; } v; v.i = ((unsigned int)u) << 16; return v.f;
}
DEVI unsigned short f2bf(float f) {
    unsigned int u = __builtin_bit_cast(unsigned int, f);
    unsigned int r = u + 0x7fffu + ((u >> 16) & 1u);   // RNE
    return (unsigned short)(r >> 16);
}
// sigmoid-form GELU: v * sigmoid(1.702 v) (validated R15, absmax 0.03125)
DEVI float gelu_sig(float v) {
    float e = __expf(-1.702f * v);
    return v * __builtin_amdgcn_rcpf(1.f + e);
}
// pack 4 f32 -> 4 fp8 e4m3 (OCP) in one u32
DEVI unsigned int pk_fp8x4(float a, float b, float c, float d) {
    int v = __builtin_amdgcn_cvt_pk_fp8_f32(a, b, 0, false);
    v = __builtin_amdgcn_cvt_pk_fp8_f32(c, d, v, true);
    return (unsigned int)v;
}
DEVI f32x4 mfma_fp8(unsigned long long a, unsigned long long b, f32x4 c) {
    return __builtin_amdgcn_mfma_f32_16x16x32_fp8_fp8((long)a, (long)b, c, 0, 0, 0);
}

// async global->LDS, 16B per lane; LDS dest is wave-uniform base + lane*16
typedef __attribute__((address_space(3))) unsigned char       lds_u8;
typedef __attribute__((address_space(1))) const unsigned char g_u8;
DEVI void gl_lds16(const void* g, void* l) {
    __builtin_amdgcn_global_load_lds((g_u8*)g, (lds_u8*)l, 16, 0, 0);
}

// ---------------------------------------------------------------------------
// K0: convert + pad weights: wq/wo/w1 -> bf16 (LN gammas folded), w2 -> fp8.
// ---------------------------------------------------------------------------
__global__ __launch_bounds__(256) void k_wconv(const float* __restrict__ wqkv,
                                               const float* __restrict__ wout,
                                               const float* __restrict__ wfc1,
                                               const float* __restrict__ wfc2,
                                               const float* __restrict__ n3g,
                                               const float* __restrict__ n4g,
                                               unsigned short* __restrict__ oq,
                                               unsigned short* __restrict__ oo,
                                               unsigned short* __restrict__ o1,
                                               unsigned short* __restrict__ o2f8) {
    int i = blockIdx.x * 256 + threadIdx.x;
    if (i < 122880) {                       // [640][192] bf16
        int r = i / 192, c = i - r * 192;
        oq[i] = (r < 576) ? f2bf(wqkv[i] * n3g[c]) : (unsigned short)0;
    } else if (i < 172032) {                // [256][192] bf16
        int j = i - 122880; int r = j / 192;
        oo[j] = (r < 192) ? f2bf(wout[j]) : (unsigned short)0;
    } else if (i < 319488) {                // [768][192] bf16
        int j = i - 172032; int c = j % 192;
        o1[j] = f2bf(wfc1[j] * n4g[c]);
    } else if (i < 417792) {                // [256][768] fp8, 2 elems/thread
        int j = i - 319488;                  // pair index over [256][384]
        int r = j / 384;
        float a = 0.f, b = 0.f;
        if (r < 192) { a = wfc2[2 * j]; b = wfc2[2 * j + 1]; }
        int pk = __builtin_amdgcn_cvt_pk_fp8_f32(a, b, 0, false);
        o2f8[j] = (unsigned short)pk;        // fp8 pairs
    }
}

// ---------------------------------------------------------------------------
// K0b: effective biases folding LN beta, plus w1 row-sums (for LN4 fold).
// ---------------------------------------------------------------------------
__global__ __launch_bounds__(256) void k_bias(const float* __restrict__ wqkv,
                                              const float* __restrict__ bqkv,
                                              const float* __restrict__ n3b,
                                              const float* __restrict__ wfc1,
                                              const float* __restrict__ bfc1,
                                              const float* __restrict__ n4b,
                                              const float* __restrict__ n4g,
                                              float* __restrict__ beffq,
                                              float* __restrict__ beff1,
                                              float* __restrict__ w1sum) {
    int wid = blockIdx.x * 4 + (threadIdx.x >> 6);
    int lane = threadIdx.x & 63;
    if (wid < 576) {
        const float* wrow = wqkv + (size_t)wid * 192;
        float s = wrow[lane] * n3b[lane] + wrow[lane + 64] * n3b[lane + 64]
                + wrow[lane + 128] * n3b[lane + 128];
#pragma unroll
        for (int off = 32; off; off >>= 1) s += __shfl_xor(s, off);
        if (lane == 0) beffq[wid] = bqkv[wid] + s;
    } else {
        int h = wid - 576;
        const float* wrow = wfc1 + (size_t)h * 192;
        float s = wrow[lane] * n4b[lane] + wrow[lane + 64] * n4b[lane + 64]
                + wrow[lane + 128] * n4b[lane + 128];
        float s2 = wrow[lane] * n4g[lane] + wrow[lane + 64] * n4g[lane + 64]
                 + wrow[lane + 128] * n4g[lane + 128];
#pragma unroll
        for (int off = 32; off; off >>= 1) { s += __shfl_xor(s, off); s2 += __shfl_xor(s2, off); }
        if (lane == 0) { beff1[h] = bfc1[h] + s; w1sum[h] = s2; }
    }
}

// ---------------------------------------------------------------------------
// K1: LayerNorm(norm3) WITHOUT affine + window partition -> h bf16.
// ---------------------------------------------------------------------------
__global__ __launch_bounds__(256) void k_ln3(const float* __restrict__ x,
                                             unsigned short* __restrict__ h) {
    int w = threadIdx.x >> 6, lane = threadIdx.x & 63;
    int token = blockIdx.x * 4 + w;
    const float* xp = x + (size_t)token * 192;
    float v0 = xp[lane], v1 = xp[lane + 64], v2 = xp[lane + 128];
    float s = v0 + v1 + v2;
#pragma unroll
    for (int off = 32; off; off >>= 1) s += __shfl_xor(s, off);
    float mean = s * (1.f / 192.f);
    float d0 = v0 - mean, d1 = v1 - mean, d2 = v2 - mean;
    float q = d0 * d0 + d1 * d1 + d2 * d2;
#pragma unroll
    for (int off = 32; off; off >>= 1) q += __shfl_xor(q, off);
    float rs = rsqrtf(q * (1.f / 192.f) + 1e-5f);
    int b  = token / (8 * 96 * 96);
    int r0 = token - b * (8 * 96 * 96);
    int d  = r0 / (96 * 96);
    int r1 = r0 - d * (96 * 96);
    int hh = r1 / 96;
    int ww = r1 - hh * 96;
    int bp = b * 144 + (hh >> 3) * 12 + (ww >> 3);
    int l  = d * 64 + (hh & 7) * 8 + (ww & 7);
    unsigned short* hp = h + ((size_t)bp * 512 + l) * 192;
    hp[lane]       = f2bf(d0 * rs);
    hp[lane + 64]  = f2bf(d1 * rs);
    hp[lane + 128] = f2bf(d2 * rs);
}

// ---------------------------------------------------------------------------
// K5: LN4 statistics only: per ybf row write (mu, rs). 1.2 MB output.
// ---------------------------------------------------------------------------
__global__ __launch_bounds__(256) void k_stats(const unsigned short* __restrict__ yb,
                                               float* __restrict__ st) {
    int sub = threadIdx.x >> 5, tl = threadIdx.x & 31;
    size_t row = (size_t)blockIdx.x * 8 + sub;
    const unsigned int* rp = reinterpret_cast<const unsigned int*>(yb + row * 192);
    float v[6];
#pragma unroll
    for (int j = 0; j < 3; j++) {
        unsigned int w = rp[tl + 32 * j];
        v[2 * j]     = bf2f((unsigned short)(w & 0xffffu));
        v[2 * j + 1] = bf2f((unsigned short)(w >> 16));
    }
    float s = v[0] + v[1] + v[2] + v[3] + v[4] + v[5];
#pragma unroll
    for (int off = 1; off < 32; off <<= 1) s += __shfl_xor(s, off);
    float mean = s * (1.f / 192.f);
    float q = 0.f;
#pragma unroll
    for (int j = 0; j < 6; j++) { float d = v[j] - mean; q += d * d; }
#pragma unroll
    for (int off = 1; off < 32; off <<= 1) q += __shfl_xor(q, off);
    float rs = rsqrtf(q * (1.f / 192.f) + 1e-5f);
    if (tl == 0) { st[row * 2] = mean; st[row * 2 + 1] = rs; }
}

// ---------------------------------------------------------------------------
// K2: 128xBN GEMM (BN = NF*32), BK-parameterized dbuf + counted-vmcnt.
// R18 config (best measured, 507.6 us): BK=32 2-buffer / 32 KB LDS /
// 3 WG/CU, swizzle (r>>1)&3, zero conflicts. R19's 2-deep variant
// (48 KB -> 2 WG/CU) regressed: at 3 WG/CU wave-level overlap already
// covers the pipeline; don't trade occupancy for depth here.
// ---------------------------------------------------------------------------
template <int EPI, int K, int NF, int BK>
__global__ __launch_bounds__(256) void k_gemm128(const unsigned short* __restrict__ A,
                                                 const unsigned short* __restrict__ Bw,
                                                 const float* __restrict__ bias,
                                                 unsigned short* __restrict__ outb,
                                                 unsigned short* __restrict__ vt,
                                                 const float* __restrict__ res,
                                                 unsigned char* __restrict__ outf8,
                                                 const float* __restrict__ stats,
                                                 const float* __restrict__ wsum) {
    __shared__ unsigned short As[2][128 * BK];
    __shared__ unsigned short Bs[2][NF * 32 * BK];
    const int tid = threadIdx.x;
    const int nwg = gridDim.x * gridDim.y;
    const int flat = blockIdx.y * gridDim.x + blockIdx.x;
    const int swz = (flat & 7) * (nwg >> 3) + (flat >> 3);
    const int bx = swz % gridDim.x, by = swz / gridDim.x;
    const int row0 = by * 128, col0 = bx * (NF * 32);
    const int wv = tid >> 6, lane = tid & 63, lr = lane & 15, lg = lane >> 4;
    const int wr = wv >> 1, wc = wv & 1;
    f32x4 acc[4][NF] = {};

    auto stage = [&](int t, int buf) {
        int k0 = t * BK;
        if constexpr (BK == 64) {
            const int sr = lane >> 3, sc = lane & 7;
#pragma unroll
            for (int i = 0; i < 4; i++) {
                int gq = wv * 4 + i;
                int r = gq * 8 + sr;
                int j = sc ^ (r & 7);
                gl_lds16(A + (size_t)(row0 + r) * K + k0 + j * 8, &As[buf][gq * 512]);
            }
#pragma unroll
            for (int i = 0; i < NF; i++) {
                int gq = wv * NF + i;
                int r = gq * 8 + sr;
                int j = sc ^ (r & 7);
                gl_lds16(Bw + (size_t)(col0 + r) * K + k0 + j * 8, &Bs[buf][gq * 512]);
            }
        } else {   // BK == 32: 1KB group = 16 rows x 4 chunks; swz const (r>>1)&3
            const int sr = lane >> 2, sc = lane & 3;
#pragma unroll
            for (int i = 0; i < 2; i++) {
                int g = wv * 2 + i;              // 8 groups of 16 rows
                int r = g * 16 + sr;
                int j = sc ^ ((r >> 1) & 3);
                gl_lds16(A + (size_t)(row0 + r) * K + k0 + j * 8, &As[buf][g * 512]);
            }
#pragma unroll
            for (int i = 0; i < 2; i++) {        // NF==4 -> 128 B rows
                int g = wv * 2 + i;
                int r = g * 16 + sr;
                int j = sc ^ ((r >> 1) & 3);
                gl_lds16(Bw + (size_t)(col0 + r) * K + k0 + j * 8, &Bs[buf][g * 512]);
            }
        }
    };

    const int NT = K / BK;
    stage(0, 0);
    for (int t = 0; t < NT; ++t) {
        int cur = t & 1;
        if (t + 1 < NT) {
            stage(t + 1, cur ^ 1);
            if constexpr (BK == 32)      asm volatile("s_waitcnt vmcnt(4)" ::: "memory");
            else if constexpr (NF == 4)  asm volatile("s_waitcnt vmcnt(8)" ::: "memory");
            else                         asm volatile("s_waitcnt vmcnt(7)" ::: "memory");
        } else {
            asm volatile("s_waitcnt vmcnt(0)" ::: "memory");
        }
        __builtin_amdgcn_sched_barrier(0);
        __builtin_amdgcn_s_barrier();
        __builtin_amdgcn_sched_barrier(0);
        if constexpr (BK == 64) {
#pragma unroll
            for (int kk = 0; kk < 64; kk += 32) {
                bf16x8 af[4], bf[NF];
#pragma unroll
                for (int m = 0; m < 4; m++) {
                    int r = wr * 64 + m * 16 + lr;
                    int j = ((kk >> 3) + lg) ^ (r & 7);
                    af[m] = __builtin_bit_cast(bf16x8,
                        *reinterpret_cast<const u32x4*>(&As[cur][r * 64 + j * 8]));
                }
#pragma unroll
                for (int n = 0; n < NF; n++) {
                    int r = wc * (NF * 16) + n * 16 + lr;
                    int j = ((kk >> 3) + lg) ^ (r & 7);
                    bf[n] = __builtin_bit_cast(bf16x8,
                        *reinterpret_cast<const u32x4*>(&Bs[cur][r * 64 + j * 8]));
                }
#pragma unroll
                for (int m = 0; m < 4; m++)
#pragma unroll
                    for (int n = 0; n < NF; n++)
                        acc[m][n] = __builtin_amdgcn_mfma_f32_16x16x32_bf16(bf[n], af[m], acc[m][n], 0, 0, 0);
            }
        } else {
            bf16x8 af[4], bf[NF];
#pragma unroll
            for (int m = 0; m < 4; m++) {
                int r = wr * 64 + m * 16 + lr;
                int j = lg ^ ((r >> 1) & 3);
                af[m] = __builtin_bit_cast(bf16x8,
                    *reinterpret_cast<const u32x4*>(&As[cur][r * 32 + j * 8]));
            }
#pragma unroll
            for (int n = 0; n < NF; n++) {
                int r = wc * (NF * 16) + n * 16 + lr;
                int j = lg ^ ((r >> 1) & 3);
                bf[n] = __builtin_bit_cast(bf16x8,
                    *reinterpret_cast<const u32x4*>(&Bs[cur][r * 32 + j * 8]));
            }
#pragma unroll
            for (int m = 0; m < 4; m++)
#pragma unroll
                for (int n = 0; n < NF; n++)
                    acc[m][n] = __builtin_amdgcn_mfma_f32_16x16x32_bf16(bf[n], af[m], acc[m][n], 0, 0, 0);
        }
        __builtin_amdgcn_sched_barrier(0);
        __builtin_amdgcn_s_barrier();
        __builtin_amdgcn_sched_barrier(0);
    }

#pragma unroll
    for (int m = 0; m < 4; m++) {
        const int arow = row0 + wr * 64 + m * 16 + lr;
        if constexpr (EPI == 0) {
#pragma unroll
            for (int n = 0; n < NF; n++) {
                const int colb = col0 + wc * (NF * 16) + n * 16 + lg * 4;
                if (colb < 384) {
                    f32x4 b4 = *reinterpret_cast<const f32x4*>(bias + colb);
                    float sc2 = (colb < 192) ? 0.1020620726159658f : 1.f;  // 1/sqrt(96) on q
                    u16x4 pk;
#pragma unroll
                    for (int rr = 0; rr < 4; rr++) pk[rr] = f2bf((acc[m][n][rr] + b4[rr]) * sc2);
                    *reinterpret_cast<u16x4*>(outb + (size_t)arow * 384 + colb) = pk;
                } else if (colb < 576) {
                    int head = (colb >= 480) ? 1 : 0;
                    int bp = arow >> 9, tok = arow & 511;
                    size_t vb = ((size_t)(bp * 2 + head) * 96 + (colb - 384 - head * 96)) * 512 + tok;
#pragma unroll
                    for (int rr = 0; rr < 4; rr++)
                        vt[vb + (size_t)rr * 512] = f2bf(acc[m][n][rr] + bias[colb + rr]);
                }
            }
        } else if constexpr (EPI == 1) {
            int bp = arow >> 9, l = arow & 511;
            int bb = bp / 144, p = bp - bb * 144;
            int hn = p / 12, wn = p - hn * 12;
            int dn = l >> 6, t_ = l & 63;
            size_t tok = ((size_t)((bb * 8 + dn) * 96 + hn * 8 + (t_ >> 3)) * 96 + wn * 8 + (t_ & 7));
#pragma unroll
            for (int n = 0; n < NF; n++) {
                const int colb = col0 + wc * (NF * 16) + n * 16 + lg * 4;   // < 192
                size_t idx = tok * 192 + colb;
                f32x4 r4 = *reinterpret_cast<const f32x4*>(res + idx);
                f32x4 b4 = *reinterpret_cast<const f32x4*>(bias + colb);
                u16x4 pk;
#pragma unroll
                for (int rr = 0; rr < 4; rr++) pk[rr] = f2bf(r4[rr] + acc[m][n][rr] + b4[rr]);
                *reinterpret_cast<u16x4*>(outb + idx) = pk;
            }
        } else {
            f32x2 st = *reinterpret_cast<const f32x2*>(stats + 2 * arow);   // mu, rs
#pragma unroll
            for (int n = 0; n < NF; n++) {
                const int colb = col0 + wc * (NF * 16) + n * 16 + lg * 4;   // < 768
                f32x4 b4 = *reinterpret_cast<const f32x4*>(bias + colb);
                f32x4 S4 = *reinterpret_cast<const f32x4*>(wsum + colb);
                float g0 = gelu_sig((acc[m][n][0] - st[0] * S4[0]) * st[1] + b4[0]);
                float g1 = gelu_sig((acc[m][n][1] - st[0] * S4[1]) * st[1] + b4[1]);
                float g2 = gelu_sig((acc[m][n][2] - st[0] * S4[2]) * st[1] + b4[2]);
                float g3 = gelu_sig((acc[m][n][3] - st[0] * S4[3]) * st[1] + b4[3]);
                *reinterpret_cast<unsigned int*>(outf8 + (size_t)arow * 768 + colb) =
                    pk_fp8x4(g0, g1, g2, g3);
            }
        }
    }
}

// ---------------------------------------------------------------------------
// K3: block-causal attention (unchanged).
// ---------------------------------------------------------------------------
__global__ __launch_bounds__(512) void k_attn(const unsigned short* __restrict__ qk,
                                              const unsigned short* __restrict__ vt,
                                              unsigned short* __restrict__ aout) {
    __shared__ unsigned short Ks[64][104];
    __shared__ unsigned short Vs[96][72];
    __shared__ unsigned short Ps[8][16][72];

    int bid = (blockIdx.x & 7) * 288 + (blockIdx.x >> 3);
    int bp = bid >> 3, rest = bid & 7, head = rest >> 2, pr = rest & 3;
    int tid = threadIdx.x, wv = tid >> 6, lane = tid & 63;
    int lr = lane & 15, lg = lane >> 4;
    int wq = wv & 3, wt = wv >> 2;
    int nk = 2 * pr + 2;

    size_t qrow0 = (size_t)bp * 512 + (size_t)(2 * pr + wt) * 64;
    const unsigned short* vbase = vt + (size_t)(bp * 2 + head) * 96 * 512;
    size_t krowb = (size_t)bp * 512;

    bf16x8 qf[3];
    {
        const unsigned short* qp = qk + (qrow0 + wq * 16 + lr) * 384 + head * 96 + lg * 8;
#pragma unroll
        for (int ks = 0; ks < 3; ks++)
            qf[ks] = __builtin_bit_cast(bf16x8, *reinterpret_cast<const u32x4*>(qp + ks * 32));
    }

    f32x4 o[6] = {};
    float m_ = -1e30f, lsum = 0.f;

    u32x4 sreg[3];
    auto issue = [&](int dnk) {
#pragma unroll
        for (int i = 0; i < 3; i++) {
            int c = tid + i * 512;
            if (c < 768) {
                int r = c / 12, cc = c - r * 12;
                sreg[i] = *reinterpret_cast<const u32x4*>(
                    qk + (krowb + dnk * 64 + r) * 384 + 192 + head * 96 + cc * 8);
            } else {
                int c2 = c - 768; int d = c2 >> 3, tb = c2 & 7;
                sreg[i] = *reinterpret_cast<const u32x4*>(
                    vbase + (size_t)d * 512 + dnk * 64 + tb * 8);
            }
        }
    };
    auto commit = [&]() {
#pragma unroll
        for (int i = 0; i < 3; i++) {
            int c = tid + i * 512;
            if (c < 768) {
                int r = c / 12, cc = c - r * 12;
                *reinterpret_cast<u32x4*>(&Ks[r][cc * 8]) = sreg[i];
            } else {
                int c2 = c - 768; int d = c2 >> 3, tb = c2 & 7;
                *reinterpret_cast<u32x4*>(&Vs[d][tb * 8]) = sreg[i];
            }
        }
    };

    issue(0);
    for (int dnk = 0; dnk < nk; ++dnk) {
        commit();
        __syncthreads();
        if (dnk + 1 < nk) issue(dnk + 1);
        if (wt == 1 || dnk < nk - 1) {
            f32x4 st[4] = {};
#pragma unroll
            for (int ks = 0; ks < 3; ks++) {
#pragma unroll
                for (int ct = 0; ct < 4; ct++) {
                    bf16x8 kf = __builtin_bit_cast(bf16x8,
                        *reinterpret_cast<const u32x4*>(&Ks[ct * 16 + lr][ks * 32 + lg * 8]));
                    st[ct] = __builtin_amdgcn_mfma_f32_16x16x32_bf16(kf, qf[ks], st[ct], 0, 0, 0);
                }
            }
            float mx = st[0][0];
#pragma unroll
            for (int ct = 0; ct < 4; ct++)
#pragma unroll
                for (int rr = 0; rr < 4; rr++) mx = fmaxf(mx, st[ct][rr]);
            mx = fmaxf(mx, __shfl_xor(mx, 16));
            mx = fmaxf(mx, __shfl_xor(mx, 32));
            float mnew = fmaxf(m_, mx);
            float corr = __expf(m_ - mnew);
            m_ = mnew;
            float ps = 0.f;
#pragma unroll
            for (int ct = 0; ct < 4; ct++) {
                u16x4 pk;
#pragma unroll
                for (int rr = 0; rr < 4; rr++) {
                    float pv = __expf(st[ct][rr] - mnew);
                    ps += pv;
                    pk[rr] = f2bf(pv);
                }
                *reinterpret_cast<u16x4*>(&Ps[wv][lr][ct * 16 + lg * 4]) = pk;
            }
            ps += __shfl_xor(ps, 16);
            ps += __shfl_xor(ps, 32);
            lsum = lsum * corr + ps;
#pragma unroll
            for (int rr = 0; rr < 4; rr++) {
                float cr = __shfl(corr, (lane & 48) | (lg * 4 + rr));
#pragma unroll
                for (int nf = 0; nf < 6; nf++) o[nf][rr] *= cr;
            }
#pragma unroll
            for (int kk = 0; kk < 2; kk++) {
                bf16x8 pf = __builtin_bit_cast(bf16x8,
                    *reinterpret_cast<const u32x4*>(&Ps[wv][lr][kk * 32 + lg * 8]));
#pragma unroll
                for (int nf = 0; nf < 6; nf++) {
                    bf16x8 vf = __builtin_bit_cast(bf16x8,
                        *reinterpret_cast<const u32x4*>(&Vs[nf * 16 + lr][kk * 32 + lg * 8]));
                    o[nf] = __builtin_amdgcn_mfma_f32_16x16x32_bf16(pf, vf, o[nf], 0, 0, 0);
                }
            }
        }
        __syncthreads();
    }

#pragma unroll
    for (int rr = 0; rr < 4; rr++) {
        float li = __shfl(lsum, (lane & 48) | (lg * 4 + rr));
        float inv = 1.f / li;
        size_t row = qrow0 + wq * 16 + lg * 4 + rr;
#pragma unroll
        for (int nf = 0; nf < 6; nf++)
            aout[row * 192 + head * 96 + nf * 16 + lr] = f2bf(o[nf][rr] * inv);
    }
}

// ---------------------------------------------------------------------------
// K6: fc2 fp8 x fp8 GEMM, 3-buffer 2-deep prefetch (unchanged).
// ---------------------------------------------------------------------------
__global__ __launch_bounds__(256) void k_fc2(const unsigned char* __restrict__ hid,
                                             const unsigned char* __restrict__ w2,
                                             const float* __restrict__ b2,
                                             const unsigned short* __restrict__ ybf,
                                             float* __restrict__ out) {
    __shared__ unsigned char As[3][128 * 64];    // 24 KB
    __shared__ unsigned char Bs[3][128 * 64];    // 24 KB
    const int tid = threadIdx.x;
    const int nwg = gridDim.x * gridDim.y;
    const int flat = blockIdx.y * gridDim.x + blockIdx.x;
    const int swz = (flat & 7) * (nwg >> 3) + (flat >> 3);
    const int bx = swz % gridDim.x, by = swz / gridDim.x;
    const int row0 = by * 128, col0 = bx * 96;
    const int wv = tid >> 6, lane = tid & 63, lr = lane & 15, lg = lane >> 4;
    const int wr = wv >> 1, wc = wv & 1;
    const int sr4 = lane >> 2, sc4 = lane & 3;
    f32x4 acc[4][3] = {};

    auto stage = [&](int t, int buf) {
        int k0 = t * 64;
#pragma unroll
        for (int i = 0; i < 2; i++) {
            int g = wv * 2 + i;
            int r = g * 16 + sr4;
            int j = sc4 ^ (r & 3);
            gl_lds16(hid + (size_t)(row0 + r) * 768 + k0 + j * 16, &As[buf][g * 1024]);
        }
#pragma unroll
        for (int i = 0; i < 2; i++) {
            int g = wv * 2 + i;
            int r = g * 16 + sr4;
            int j = sc4 ^ (r & 3);
            gl_lds16(w2 + (size_t)(col0 + r) * 768 + k0 + j * 16, &Bs[buf][g * 1024]);
        }
    };

    stage(0, 0);
    stage(1, 1);
    int cur = 0;
    for (int t = 0; t < 12; ++t) {
        if (t + 2 < 12) {
            stage(t + 2, (t + 2) % 3);
            asm volatile("s_waitcnt vmcnt(8)" ::: "memory");
        } else if (t + 1 < 12) {
            asm volatile("s_waitcnt vmcnt(4)" ::: "memory");
        } else {
            asm volatile("s_waitcnt vmcnt(0)" ::: "memory");
        }
        __builtin_amdgcn_sched_barrier(0);
        __builtin_amdgcn_s_barrier();
        __builtin_amdgcn_sched_barrier(0);
#pragma unroll
        for (int kk = 0; kk < 2; kk++) {
            const int cc = kk * 2 + (lg >> 1);
            const int off = (lg & 1) * 8;
            unsigned long long af[4], bfr[3];
#pragma unroll
            for (int m = 0; m < 4; m++) {
                int r = wr * 64 + m * 16 + lr;
                int j = cc ^ (r & 3);
                af[m] = *reinterpret_cast<const unsigned long long*>(
                    &As[cur][r * 64 + j * 16 + off]);
            }
#pragma unroll
            for (int n = 0; n < 3; n++) {
                int r = wc * 48 + n * 16 + lr;
                int j = cc ^ (r & 3);
                bfr[n] = *reinterpret_cast<const unsigned long long*>(
                    &Bs[cur][r * 64 + j * 16 + off]);
            }
#pragma unroll
            for (int m = 0; m < 4; m++)
#pragma unroll
                for (int n = 0; n < 3; n++)
                    acc[m][n] = mfma_fp8(bfr[n], af[m], acc[m][n]);
        }
        __builtin_amdgcn_sched_barrier(0);
        __builtin_amdgcn_s_barrier();
        __builtin_amdgcn_sched_barrier(0);
        cur = (cur + 1) % 3;
    }

#pragma unroll
    for (int m = 0; m < 4; m++) {
        const int arow = row0 + wr * 64 + m * 16 + lr;
#pragma unroll
        for (int n = 0; n < 3; n++) {
            const int colb = col0 + wc * 48 + n * 16 + lg * 4;   // < 192
            size_t idx = (size_t)arow * 192 + colb;
            f32x4 b4 = *reinterpret_cast<const f32x4*>(b2 + colb);
            u16x4 rb = *reinterpret_cast<const u16x4*>(ybf + idx);
            f32x4 o4;
#pragma unroll
            for (int rr = 0; rr < 4; rr++) o4[rr] = bf2f(rb[rr]) + acc[m][n][rr] + b4[rr];
            *reinterpret_cast<f32x4*>(out + idx) = o4;
        }
    }
}

// ---------------------------------------------------------------------------
// Launcher. ws arena (~342 MB), unchanged.
// d_out written only by k_fc2 (fully rewritten each call => replay safe).
// ---------------------------------------------------------------------------
extern "C" void kernel_launch(void* const* d_in, const int* in_sizes, int n_in,
                              void* d_out, int out_size, void* d_ws, size_t ws_size,
                              hipStream_t stream) {
    const float* x    = (const float*)d_in[0];
    const float* n3g  = (const float*)d_in[1];
    const float* n3b  = (const float*)d_in[2];
    const float* wqkv = (const float*)d_in[3];
    const float* bqkv = (const float*)d_in[4];
    const float* wout = (const float*)d_in[5];
    const float* bout = (const float*)d_in[6];
    const float* n4g  = (const float*)d_in[7];
    const float* n4b  = (const float*)d_in[8];
    const float* wfc1 = (const float*)d_in[9];
    const float* bfc1 = (const float*)d_in[10];
    const float* wfc2 = (const float*)d_in[11];
    const float* bfc2 = (const float*)d_in[12];
    float* out = (float*)d_out;

    char* ws = (char*)d_ws;
    unsigned short* qk     = (unsigned short*)(ws + 0);
    unsigned char*  hidden = (unsigned char*)(ws + 0);            // aliases qk (dead)
    unsigned short* vt     = (unsigned short*)(ws + 113246208);
    unsigned short* attn   = (unsigned short*)(ws + 169869312);
    unsigned short* ybf    = (unsigned short*)(ws + 226492416);
    unsigned short* h      = (unsigned short*)(ws + 283115520);
    unsigned short* wq_bf  = (unsigned short*)(ws + 339738624);
    unsigned short* wo_bf  = (unsigned short*)(ws + 339984384);
    unsigned short* w1_bf  = (unsigned short*)(ws + 340082688);
    unsigned short* w2_f8p = (unsigned short*)(ws + 340377600);   // fp8 pairs
    unsigned char*  w2_f8  = (unsigned char*)(ws + 340377600);
    float*          beffq  = (float*)(ws + 340574208);
    float*          beff1  = (float*)(ws + 340576512);
    float*          w1sum  = (float*)(ws + 340579584);
    float*          stats  = (float*)(ws + 340582656);            // [N][2] mu,rs

    k_wconv<<<1632, 256, 0, stream>>>(wqkv, wout, wfc1, wfc2, n3g, n4g, wq_bf, wo_bf, w1_bf, w2_f8p);
    k_bias<<<336, 256, 0, stream>>>(wqkv, bqkv, n3b, wfc1, bfc1, n4b, n4g, beffq, beff1, w1sum);
    k_ln3<<<36864, 256, 0, stream>>>(x, h);
    k_gemm128<0, 192, 4, 32><<<dim3(5, 1152), 256, 0, stream>>>(h, wq_bf, beffq, qk, vt, nullptr, nullptr, nullptr, nullptr);
    k_attn<<<2304, 512, 0, stream>>>(qk, vt, attn);
    k_gemm128<1, 192, 3, 64><<<dim3(2, 1152), 256, 0, stream>>>(attn, wo_bf, bout, ybf, nullptr, x, nullptr, nullptr, nullptr);
    k_stats<<<18432, 256, 0, stream>>>(ybf, stats);
    k_gemm128<2, 192, 4, 32><<<dim3(6, 1152), 256, 0, stream>>>(ybf, w1_bf, beff1, nullptr, nullptr, nullptr, hidden, stats, w1sum);
    k_fc2<<<dim3(2, 1152), 256, 0, stream>>>(hidden, w2_f8, bfc2, ybf, out);
}